// Round 13
// baseline (1440.647 us; speedup 1.0000x reference)
//
#include <hip/hip_runtime.h>
#include <hip/hip_bf16.h>

#define D_MODEL 4096
#define D_FF    11008
#define NTOK    4096   // 2 * 2048 tokens

typedef unsigned int u32;
typedef unsigned short u16;
using f32x4   = __attribute__((ext_vector_type(4))) float;
using bf16x8  = __attribute__((ext_vector_type(8))) short;
using ushort8 = __attribute__((ext_vector_type(8))) unsigned short;
using int4v   = __attribute__((ext_vector_type(4))) int;
using float4v = __attribute__((ext_vector_type(4))) float;

__device__ __forceinline__ u16 bf16_rn(float f) {
    u32 u = __builtin_bit_cast(u32, f);
    u += 0x7FFFu + ((u >> 16) & 1u);
    return (u16)(u >> 16);
}
__device__ __forceinline__ u16 bf16_from_int(int v) {
    float f = (float)v;   // exact for |v| <= 127
    return (u16)(__builtin_bit_cast(u32, f) >> 16);
}
__device__ __forceinline__ void gload16(const void* g, void* l) {
    __builtin_amdgcn_global_load_lds(
        (const __attribute__((address_space(1))) u32*)g,
        (__attribute__((address_space(3))) u32*)l, 16, 0, 0);
}

// ---------------- x fp32 -> bf16 ----------------
__global__ void k_cvt_x(const float* __restrict__ x, u16* __restrict__ xb) {
    int i = (blockIdx.x * 256 + threadIdx.x) * 8;
    float4v a = *(const float4v*)(x + i);
    float4v b = *(const float4v*)(x + i + 4);
    ushort8 o;
    o[0] = bf16_rn(a[0]); o[1] = bf16_rn(a[1]); o[2] = bf16_rn(a[2]); o[3] = bf16_rn(a[3]);
    o[4] = bf16_rn(b[0]); o[5] = bf16_rn(b[1]); o[6] = bf16_rn(b[2]); o[7] = bf16_rn(b[3]);
    *(ushort8*)(xb + i) = o;
}

// ---------------- weight int32 -> bf16 ----------------
__global__ void k_cvt_w(const int* __restrict__ w, u16* __restrict__ wb, int n) {
    int i = (blockIdx.x * 256 + threadIdx.x) * 8;
    if (i >= n) return;
    int4v a = *(const int4v*)(w + i);
    int4v b = *(const int4v*)(w + i + 4);
    ushort8 o;
    o[0] = bf16_from_int(a[0]); o[1] = bf16_from_int(a[1]);
    o[2] = bf16_from_int(a[2]); o[3] = bf16_from_int(a[3]);
    o[4] = bf16_from_int(b[0]); o[5] = bf16_from_int(b[1]);
    o[6] = bf16_from_int(b[2]); o[7] = bf16_from_int(b[3]);
    *(ushort8*)(wb + i) = o;
}

// =====================================================================
// 256x256 GEMM, ONE barrier per K-tile, cross-phase read/MFMA rotation:
// phase T = { LGKM(0); VMC(0); BAR; stage(T+2 -> CUR);
//             MFMA(T)x64 interleaved with frag-reads(T+1 <- NXT) at
//             register-death points (rotation in-place) }.
// Soundness (barrier-chained, no timing arguments):
//   WAR(stage->CUR): frags(T) were read from CUR last phase; every
//     wave's LGKM(0) drains them BEFORE the BAR; stage issues after.
//   RAW(reads(T+1)<-NXT): NXT staged last phase; every wave's VMC(0)
//     drains its slice BEFORE the BAR; reads issue after.
//   MFMA operands: compiler-visible C++ ds_reads -> compiler inserts
//     precise counted lgkmcnt before dependent MFMAs.
// 8 waves (2Mx4N), BK=64, dbuf 128 KiB LDS, XOR-granule swizzle,
// gload_lds staging (pre-swizzled source), setprio around MFMA.
// EPI: 3 = fused gate+up (B0=gate rows, B1=up rows, same f-cols)
//      2 = down (of32 = acc*scale)
// =====================================================================

// element offsets: A(buf,h) = buf*32768 + h*8192; B adds +16384
#define READA(AA, BUF, MH) {                                                  \
  _Pragma("unroll") for (int mm = 0; mm < 4; ++mm) {                          \
    AA[mm][0] = *(const bf16x8*)&lds[(BUF)*32768 + (MH)*8192 + mm*1024 + aoffE + g0E]; \
    AA[mm][1] = *(const bf16x8*)&lds[(BUF)*32768 + (MH)*8192 + mm*1024 + aoffE + g1E]; } }

#define READB(BB, BUF, NH) {                                                  \
  _Pragma("unroll") for (int nn = 0; nn < 2; ++nn) {                          \
    BB[nn][0] = *(const bf16x8*)&lds[(BUF)*32768 + 16384 + (NH)*8192 + nn*1024 + boffE + g0E]; \
    BB[nn][1] = *(const bf16x8*)&lds[(BUF)*32768 + 16384 + (NH)*8192 + nn*1024 + boffE + g1E]; } }

#define MFMA16(MH, NH, AA, BB)                                                \
  _Pragma("unroll") for (int mm = 0; mm < 4; ++mm)                            \
  _Pragma("unroll") for (int nn = 0; nn < 2; ++nn)                            \
  _Pragma("unroll") for (int kk = 0; kk < 2; ++kk)                            \
    acc[(MH)*4+mm][(NH)*2+nn] = __builtin_amdgcn_mfma_f32_16x16x32_bf16(      \
        AA[mm][kk], BB[nn][kk], acc[(MH)*4+mm][(NH)*2+nn], 0, 0, 0);

// LDS element offsets for staging (ushort units)
#define REGA(BUF, H) ((BUF)*32768 + (H)*8192)
#define REGB(BUF, H) ((BUF)*32768 + 16384 + (H)*8192)

#define STAGE_A(BUF, MH, K0) {                                                \
  const u16* _s = A + a_sbase + (size_t)(MH)*128*K + (K0);                    \
  gload16(_s,                &lds[REGA(BUF, MH) + wave*512]);                 \
  gload16(_s + (size_t)64*K, &lds[REGA(BUF, MH) + (8+wave)*512]); }

// NH is a literal 0/1 at every use -> base select folds at compile time
#define STAGE_B(BUF, NH, K0) {                                                \
  const u16* _s = ((NH) ? b1base : b0base) + (K0);                            \
  gload16(_s,                &lds[REGB(BUF, NH) + wave*512]);                 \
  gload16(_s + (size_t)64*K, &lds[REGB(BUF, NH) + (8+wave)*512]); }

#define BAR   __builtin_amdgcn_s_barrier()
#define PRIO1 __builtin_amdgcn_s_setprio(1)
#define PRIO0 __builtin_amdgcn_s_setprio(0)
#define VMC(N)  asm volatile("s_waitcnt vmcnt(" #N ")" ::: "memory")
#define LGKM(N) asm volatile("s_waitcnt lgkmcnt(" #N ")" ::: "memory")

// Quadrant order (1,1),(1,0),(0,1),(0,0); deaths: a1 after 2nd, b1 after
// 3rd, b0/a0 after 4th -> reads rotate in at death points.
#define PHASE(CUR, NXT, T) {                                                  \
  LGKM(0); VMC(0); BAR;                                                       \
  if ((T)+2 < nt) { STAGE_A(CUR, 0, ((T)+2) << 6);                            \
                    STAGE_A(CUR, 1, ((T)+2) << 6);                            \
                    STAGE_B(CUR, 0, ((T)+2) << 6);                            \
                    STAGE_B(CUR, 1, ((T)+2) << 6); }                          \
  PRIO1; MFMA16(1, 1, a1, b1); PRIO0;                                         \
  PRIO1; MFMA16(1, 0, a1, b0); PRIO0;                                         \
  if ((T)+1 < nt) READA(a1, NXT, 1);                                          \
  PRIO1; MFMA16(0, 1, a0, b1); PRIO0;                                         \
  if ((T)+1 < nt) READB(b1, NXT, 1);                                          \
  PRIO1; MFMA16(0, 0, a0, b0); PRIO0;                                         \
  if ((T)+1 < nt) { READB(b0, NXT, 0); READA(a0, NXT, 0); } }

template<int EPI>
__global__ __launch_bounds__(512, 2) void k_gemm256(
    const u16* __restrict__ A,
    const u16* __restrict__ B0, const u16* __restrict__ B1,
    const float* __restrict__ sc0, const float* __restrict__ sc1,
    u16* __restrict__ obf, float* __restrict__ of32,
    int K, int NBN, int ldc)
{
    __shared__ __align__(16) u16 lds[65536];   // 128 KiB

    constexpr int S0 = (EPI == 3) ? 128 : 256;   // B row-block stride per bn
    constexpr int H1 = (EPI == 3) ? 0   : 128;   // row offset of half1 in B1

    const int tid  = threadIdx.x;
    const int lane = tid & 63;
    const int wave = tid >> 6;          // 0..7
    const int wm   = wave >> 2;         // 0..1
    const int wn   = wave & 3;          // 0..3

    // XCD-aware bijective swizzle (m204); bm slow, bn fast (R10)
    const int nwg  = 16 * NBN;
    const int orig = blockIdx.x;
    const int qq   = nwg >> 3, rr = nwg & 7;
    const int xcd  = orig & 7;
    const int swz  = (xcd < rr ? xcd*(qq+1) : rr*(qq+1) + (xcd-rr)*qq) + (orig >> 3);
    const int bm   = swz / NBN;
    const int bn   = swz % NBN;

    // fragment-read per-thread constants (u16-element offsets)
    const int r    = lane & 15;
    const int sQ   = lane >> 4;         // 0..3
    const int x7   = r & 7;
    const int g0E  = (sQ ^ x7) * 8;           // kk=0 granule
    const int g1E  = ((4 | sQ) ^ x7) * 8;     // kk=1 granule
    const int aoffE = (wm*64 + r) * 64;
    const int boffE = (wn*32 + r) * 64;

    // stage per-thread constants (inverse swizzle on the global source)
    const int lrow = lane >> 3;                       // 0..7
    const int goff = ((lane & 7) ^ lrow) * 8;         // elems within 64-col row
    const size_t a_sbase = (size_t)(bm*256 + wave*8 + lrow) * K + goff;
    const u16* b0base = B0 + (size_t)(bn*S0 +      wave*8 + lrow) * K + goff;
    const u16* b1base = B1 + (size_t)(bn*S0 + H1 + wave*8 + lrow) * K + goff;

    f32x4 acc[8][4];
#pragma unroll
    for (int m = 0; m < 8; ++m)
#pragma unroll
        for (int n = 0; n < 4; ++n) acc[m][n] = (f32x4){0.f, 0.f, 0.f, 0.f};

    const int nt = K >> 6;              // K/64: 64 (K=4096) or 172 (K=11008), even

    // ---- prologue: tile0 -> buf0 [8 gloads]; tile1 -> buf1 [8 gloads]
    STAGE_A(0, 0, 0); STAGE_A(0, 1, 0); STAGE_B(0, 0, 0); STAGE_B(0, 1, 0);
    STAGE_A(1, 0, 64); STAGE_A(1, 1, 64); STAGE_B(1, 0, 64); STAGE_B(1, 1, 64);
    VMC(8);                              // tile0's 8 gloads complete per-wave
    BAR;                                 // all waves' tile0 staging complete

    bf16x8 a0[4][2], a1[4][2], b0[2][2], b1[2][2];
    // tile0 fragment reads (consumed in phase 0)
    READA(a1, 0, 1); READB(b1, 0, 1); READB(b0, 0, 0); READA(a0, 0, 0);

    for (int t = 0; t < nt; t += 2) {
        PHASE(0, 1, t);
        PHASE(1, 0, t + 1);
    }

    // ---- epilogue
    if constexpr (EPI == 3) {
        // fused gate+up: acc[m][n] (gate) pairs with acc[m][n+2] (up), same f
#pragma unroll
        for (int n = 0; n < 2; ++n) {
            const int f = bn*128 + wn*32 + n*16 + r;
            const float gsc = sc0[f];
            const float usc = sc1[f];
#pragma unroll
            for (int m = 0; m < 8; ++m) {
                const int row = bm*256 + (m>>2)*128 + wm*64 + (m&3)*16 + sQ*4;
#pragma unroll
                for (int q = 0; q < 4; ++q) {
                    const float g = acc[m][n][q] * gsc;
                    const float u = acc[m][n+2][q] * usc;
                    const float s2 = g / (1.0f + __expf(-g));
                    obf[(size_t)(row + q) * ldc + f] = bf16_rn(s2 * u);
                }
            }
        }
    } else {
#pragma unroll
        for (int n = 0; n < 4; ++n) {
            const int col = bn*256 + (n>>1)*128 + wn*32 + (n&1)*16 + r;
            const float sc = sc0[col];
#pragma unroll
            for (int m = 0; m < 8; ++m) {
                const int row = bm*256 + (m>>2)*128 + wm*64 + (m&3)*16 + sQ*4;
#pragma unroll
                for (int q = 0; q < 4; ++q)
                    of32[(size_t)(row + q) * ldc + col] = acc[m][n][q] * sc;
            }
        }
    }
}

extern "C" void kernel_launch(void* const* d_in, const int* in_sizes, int n_in,
                              void* d_out, int out_size, void* d_ws, size_t ws_size,
                              hipStream_t stream) {
    const float* x  = (const float*)d_in[0];
    const int*   gw = (const int*)d_in[1];
    const float* gs = (const float*)d_in[2];
    const int*   uw = (const int*)d_in[3];
    const float* us = (const float*)d_in[4];
    const int*   dw = (const int*)d_in[5];
    const float* ds = (const float*)d_in[6];
    float* out = (float*)d_out;

    const size_t XB = (size_t)NTOK * D_MODEL * 2;   // 33.5 MB  x bf16
    const size_t WB = (size_t)D_FF * D_MODEL * 2;   // 90.2 MB  weight bf16
    const size_t HB = (size_t)NTOK * D_FF * 2;      // 90.2 MB  h bf16
    if (ws_size < XB + 2 * WB + HB) return;         // loud failure (poisoned out)

    char* ws = (char*)d_ws;
    u16* xb  = (u16*)ws;
    u16* wbG = (u16*)(ws + XB);
    u16* wbU = (u16*)(ws + XB + WB);
    u16* hb  = (u16*)(ws + XB + 2 * WB);

    const int wn_elems = D_FF * D_MODEL;            // 45,088,768
    const int wgrid = wn_elems / (8 * 256);

    k_cvt_x<<<(NTOK * D_MODEL) / (8 * 256), 256, 0, stream>>>(x, xb);
    k_cvt_w<<<wgrid, 256, 0, stream>>>(gw, wbG, wn_elems);
    k_cvt_w<<<wgrid, 256, 0, stream>>>(uw, wbU, wn_elems);

    // fused: h = bf16( silu((xb.gw^T)*gs) * (xb.uw^T)*us )
    k_gemm256<3><<<16 * (D_FF / 128), 512, 0, stream>>>(
        xb, wbG, wbU, gs, us, hb, nullptr, D_MODEL, D_FF / 128, D_FF);

    // down: out = (h . dw^T) * ds   (reuse gate-weight buffer)
    k_cvt_w<<<wgrid, 256, 0, stream>>>(dw, wbG, wn_elems);
    k_gemm256<2><<<16 * (D_MODEL / 256), 512, 0, stream>>>(
        hb, wbG, wbG, ds, nullptr, nullptr, out, D_FF, D_MODEL / 256, D_MODEL);
}

// Round 14
// 855.300 us; speedup vs baseline: 1.6844x; 1.6844x over previous
//
#include <hip/hip_runtime.h>
#include <hip/hip_bf16.h>

#define D_MODEL 4096
#define D_FF    11008
#define NTOK    4096   // 2 * 2048 tokens

typedef unsigned int u32;
typedef unsigned short u16;
typedef signed char s8;
using f32x4   = __attribute__((ext_vector_type(4))) float;
using i32x4   = __attribute__((ext_vector_type(4))) int;
using bf16x8  = __attribute__((ext_vector_type(8))) short;
using ushort8 = __attribute__((ext_vector_type(8))) unsigned short;
using u32x2   = __attribute__((ext_vector_type(2))) u32;
using int4v   = __attribute__((ext_vector_type(4))) int;
using float4v = __attribute__((ext_vector_type(4))) float;

#define XSCALE (6.0f / 127.0f)

__device__ __forceinline__ u16 bf16_rn(float f) {
    u32 u = __builtin_bit_cast(u32, f);
    u += 0x7FFFu + ((u >> 16) & 1u);
    return (u16)(u >> 16);
}
__device__ __forceinline__ u16 bf16_from_int(int v) {
    float f = (float)v;   // exact for |v| <= 127
    return (u16)(__builtin_bit_cast(u32, f) >> 16);
}
__device__ __forceinline__ void gload16(const void* g, void* l) {
    __builtin_amdgcn_global_load_lds(
        (const __attribute__((address_space(1))) u32*)g,
        (__attribute__((address_space(3))) u32*)l, 16, 0, 0);
}

// ---------------- x fp32 -> s8 (global scale) ----------------
__global__ void k_quant_x(const float* __restrict__ x, s8* __restrict__ xq) {
    const float invs = 127.0f / 6.0f;
    int i = (blockIdx.x * 256 + threadIdx.x) * 8;
    float4v a = *(const float4v*)(x + i);
    float4v b = *(const float4v*)(x + i + 4);
    u32 w0 = 0, w1 = 0;
#pragma unroll
    for (int e = 0; e < 4; ++e) {
        int qa = (int)rintf(a[e] * invs);
        qa = qa > 127 ? 127 : (qa < -127 ? -127 : qa);
        int qb = (int)rintf(b[e] * invs);
        qb = qb > 127 ? 127 : (qb < -127 ? -127 : qb);
        w0 |= (u32)(qa & 255) << (8 * e);
        w1 |= (u32)(qb & 255) << (8 * e);
    }
    *(u32x2*)(xq + i) = (u32x2){w0, w1};
}

// ---------------- weight int32 -> s8 ----------------
__global__ void k_cvt_w8(const int* __restrict__ w, s8* __restrict__ wb) {
    int i = (blockIdx.x * 256 + threadIdx.x) * 8;
    int4v a = *(const int4v*)(w + i);
    int4v b = *(const int4v*)(w + i + 4);
    u32 w0 = 0, w1 = 0;
#pragma unroll
    for (int e = 0; e < 4; ++e) {
        w0 |= (u32)(a[e] & 255) << (8 * e);
        w1 |= (u32)(b[e] & 255) << (8 * e);
    }
    *(u32x2*)(wb + i) = (u32x2){w0, w1};
}

// ---------------- weight int32 -> bf16 (for down GEMM) ----------------
__global__ void k_cvt_w(const int* __restrict__ w, u16* __restrict__ wb) {
    int i = (blockIdx.x * 256 + threadIdx.x) * 8;
    int4v a = *(const int4v*)(w + i);
    int4v b = *(const int4v*)(w + i + 4);
    ushort8 o;
    o[0] = bf16_from_int(a[0]); o[1] = bf16_from_int(a[1]);
    o[2] = bf16_from_int(a[2]); o[3] = bf16_from_int(a[3]);
    o[4] = bf16_from_int(b[0]); o[5] = bf16_from_int(b[1]);
    o[6] = bf16_from_int(b[2]); o[7] = bf16_from_int(b[3]);
    *(ushort8*)(wb + i) = o;
}

// =====================================================================
// FUSED gate+up GEMM in INT8: 256 tokens x 128 f-cols per block, BK=64,
// mfma_i32_16x16x64_i8 (one k-step per MFMA, exact i32 accumulation).
// LDS 64 KiB: per buf {A: 256x64 s8 = 16K, B: [gate128|up128]x64 = 16K}.
// i8 halves LDS read/write bytes vs bf16 -> halves the LDS-BW floor the
// 256^2 bf16 kernel is bound by (192+64 KB -> 96+32 KB per tile).
// Schedule = faithful R12 2-phase port, counts re-derived (4 gloads
// per tile per wave -> vmcnt(3) gate):
//  Ph1: read a0(4)+b(4); stage Ah1(t+1)->NXT; BAR; MFMA mh0 x16; BAR
//  Ph2: read a1(4); stage Ah0(t+2)+B(t+2)->CUR; BAR; MFMA mh1 x16;
//       vmcnt(3|0); BAR
// WAR: each region's overwrite issues >=1 barrier after its readers'
// in-phase operand-drain. RAW: vmcnt(3) leaves only tile-(t+2) loads
// in flight -> tile t+1 complete.
// Swizzle: 16B granule q at position q^(row&3) within the 64B row
// (both stage-source and read; residual 2-way conflict is free).
// Epilogue: h = bf16( silu(accG*S*gs) * (accU*S*us) ).
// =====================================================================

#define BAR   __builtin_amdgcn_s_barrier()
#define PRIO1 __builtin_amdgcn_s_setprio(1)
#define PRIO0 __builtin_amdgcn_s_setprio(0)
#define VMC(N)  asm volatile("s_waitcnt vmcnt(" #N ")" ::: "memory")

// A granule: buf*32768 + mh*8192 + mm*1024 + (wm*64+r)*64 + qsw
#define RD_A8(AA, BUF, MH) {                                                  \
  _Pragma("unroll") for (int mm = 0; mm < 4; ++mm)                            \
    AA[mm] = *(const i32x4*)&lds8[(BUF)*32768 + (MH)*8192 + mm*1024 + adA]; }

#define RD_B8(BB, BUF) {                                                      \
  _Pragma("unroll") for (int nn = 0; nn < 4; ++nn)                            \
    BB[nn] = *(const i32x4*)&lds8[(BUF)*32768 + 16384 + (nn>>1)*8192 +        \
                                  (nn&1)*1024 + adB]; }

#define MFMA_I8(MH, AA, BB)                                                   \
  _Pragma("unroll") for (int mm = 0; mm < 4; ++mm)                            \
  _Pragma("unroll") for (int nn = 0; nn < 4; ++nn)                            \
    acc[(MH)*4+mm][nn] = __builtin_amdgcn_mfma_i32_16x16x64_i8(               \
        AA[mm], BB[nn], acc[(MH)*4+mm][nn], 0, 0, 0);

// one gload: rows mh*128 + wave*16 + (lane>>2), granule lane&3
#define STAGE_AH(BUF, MH, K0) {                                               \
  gload16(xq + (size_t)(bm*256 + (MH)*128 + wave*16 + (lane>>2))*K + (K0) + asw, \
          &lds8[(BUF)*32768 + (MH)*8192 + wave*1024 + lane*16]); }

#define STAGE_B2(BUF, K0) {                                                   \
  gload16(wg8 + (size_t)(bn*128 + wave*16 + (lane>>2))*K + (K0) + asw,        \
          &lds8[(BUF)*32768 + 16384 + wave*1024 + lane*16]);                  \
  gload16(wu8 + (size_t)(bn*128 + wave*16 + (lane>>2))*K + (K0) + asw,        \
          &lds8[(BUF)*32768 + 24576 + wave*1024 + lane*16]); }

#define TILE_I8(CUR, NXT, T) {                                                \
  RD_A8(a0, CUR, 0); RD_B8(bb, CUR);                                          \
  if ((T)+1 < nt) STAGE_AH(NXT, 1, ((T)+1) << 6);                             \
  BAR; PRIO1; MFMA_I8(0, a0, bb); PRIO0; BAR;                                 \
  RD_A8(a1, CUR, 1);                                                          \
  if ((T)+2 < nt) { STAGE_AH(CUR, 0, ((T)+2) << 6);                           \
                    STAGE_B2(CUR, ((T)+2) << 6); }                            \
  BAR; PRIO1; MFMA_I8(1, a1, bb); PRIO0;                                      \
  if ((T)+2 < nt) { VMC(3); } else { VMC(0); }                                \
  BAR; }

__global__ __launch_bounds__(512, 2) void k_fusedgu_i8(
    const s8* __restrict__ xq,
    const s8* __restrict__ wg8, const s8* __restrict__ wu8,
    const float* __restrict__ gs, const float* __restrict__ us,
    u16* __restrict__ hb, int K, int NBN, int ldc)
{
    __shared__ __align__(16) char lds8[65536];   // 64 KiB

    const int tid  = threadIdx.x;
    const int lane = tid & 63;
    const int wave = tid >> 6;          // 0..7
    const int wm   = wave >> 2;         // 0..1
    const int wn   = wave & 3;          // 0..3

    // XCD-aware bijective swizzle; bm slow, bn fast
    const int nwg  = 16 * NBN;
    const int orig = blockIdx.x;
    const int qq   = nwg >> 3, rr = nwg & 7;
    const int xcd  = orig & 7;
    const int swz  = (xcd < rr ? xcd*(qq+1) : rr*(qq+1) + (xcd-rr)*qq) + (orig >> 3);
    const int bm   = swz / NBN;
    const int bn   = swz % NBN;

    // fragment-read constants (bytes)
    const int r    = lane & 15;
    const int sQ   = lane >> 4;                  // k-granule 0..3
    const int qsw  = (sQ ^ (r & 3)) * 16;        // swizzled granule byte off
    const int adA  = (wm*64 + r) * 64 + qsw;
    const int adB  = (wn*32 + r) * 64 + qsw;

    // stage source swizzle: granule position p=lane&3 holds quarter p^(row&3)
    const int asw  = (((lane & 3) ^ ((lane >> 2) & 3))) * 16;

    i32x4 acc[8][4];
#pragma unroll
    for (int m = 0; m < 8; ++m)
#pragma unroll
        for (int n = 0; n < 4; ++n) acc[m][n] = (i32x4){0, 0, 0, 0};

    const int nt = K >> 6;              // 64 for K=4096 (even)

    // prologue: tile0 fully [4], tile1 {Ah0, B} [3]; Ah1(1) staged in t0-Ph1
    STAGE_AH(0, 0, 0); STAGE_AH(0, 1, 0); STAGE_B2(0, 0);
    STAGE_AH(1, 0, 64); STAGE_B2(1, 64);
    VMC(3);                              // tile0's 4 gloads complete
    BAR;

    i32x4 a0[4], a1[4], bb[4];
    for (int t = 0; t < nt; t += 2) {
        TILE_I8(0, 1, t);
        TILE_I8(1, 0, t + 1);
    }

    // epilogue: n=0,1 -> gate; n=2,3 -> up (same f-cols)
#pragma unroll
    for (int n = 0; n < 2; ++n) {
        const int f = bn*128 + wn*32 + n*16 + r;
        const float gsc = XSCALE * gs[f];
        const float usc = XSCALE * us[f];
#pragma unroll
        for (int m = 0; m < 8; ++m) {
            const int row = bm*256 + (m>>2)*128 + wm*64 + (m&3)*16 + sQ*4;
#pragma unroll
            for (int q = 0; q < 4; ++q) {
                const float g = (float)acc[m][n][q] * gsc;
                const float u = (float)acc[m][n+2][q] * usc;
                const float s2 = g / (1.0f + __expf(-g));
                hb[(size_t)(row + q) * ldc + f] = bf16_rn(s2 * u);
            }
        }
    }
}

// =====================================================================
// DOWN GEMM (bf16) — exact R12 structure (proven): 256x256, 2-phase,
// vmcnt(6), XOR-granule swizzle, gload_lds staging, setprio.
// out[m,d] = (h . dw^T)[m,d] * ds[d]   (fp32 out)
// =====================================================================

#define READA(AA, BUF, MH) {                                                  \
  _Pragma("unroll") for (int mm = 0; mm < 4; ++mm) {                          \
    AA[mm][0] = *(const bf16x8*)&lds[(BUF)*32768 + (MH)*8192 + mm*1024 + aoffE + g0E]; \
    AA[mm][1] = *(const bf16x8*)&lds[(BUF)*32768 + (MH)*8192 + mm*1024 + aoffE + g1E]; } }

#define READB(BB, BUF, NH) {                                                  \
  _Pragma("unroll") for (int nn = 0; nn < 2; ++nn) {                          \
    BB[nn][0] = *(const bf16x8*)&lds[(BUF)*32768 + 16384 + (NH)*8192 + nn*1024 + boffE + g0E]; \
    BB[nn][1] = *(const bf16x8*)&lds[(BUF)*32768 + 16384 + (NH)*8192 + nn*1024 + boffE + g1E]; } }

#define MFMA16(MH, NH, AA, BB)                                                \
  _Pragma("unroll") for (int mm = 0; mm < 4; ++mm)                            \
  _Pragma("unroll") for (int nn = 0; nn < 2; ++nn)                            \
  _Pragma("unroll") for (int kk = 0; kk < 2; ++kk)                            \
    acc[(MH)*4+mm][(NH)*2+nn] = __builtin_amdgcn_mfma_f32_16x16x32_bf16(      \
        AA[mm][kk], BB[nn][kk], acc[(MH)*4+mm][(NH)*2+nn], 0, 0, 0);

#define REGA(BUF, H) ((BUF)*32768 + (H)*8192)
#define REGB(BUF, H) ((BUF)*32768 + 16384 + (H)*8192)

#define STAGE_A(BUF, MH, K0) {                                                \
  const u16* _s = A + a_sbase + (size_t)(MH)*128*K + (K0);                    \
  gload16(_s,                &lds[REGA(BUF, MH) + wave*512]);                 \
  gload16(_s + (size_t)64*K, &lds[REGA(BUF, MH) + (8+wave)*512]); }

#define STAGE_B(BUF, NH, K0) {                                                \
  const u16* _s = ((NH) ? b1base : b0base) + (K0);                            \
  gload16(_s,                &lds[REGB(BUF, NH) + wave*512]);                 \
  gload16(_s + (size_t)64*K, &lds[REGB(BUF, NH) + (8+wave)*512]); }

#define TILE2(CUR, NXT, T) {                                                  \
  READA(a0, CUR, 0); READB(b0, CUR, 0); READB(b1, CUR, 1);                    \
  if ((T)+1 < nt) STAGE_A(NXT, 1, ((T)+1) << 6);                              \
  BAR; PRIO1;                                                                 \
  MFMA16(0, 0, a0, b0); MFMA16(0, 1, a0, b1);                                 \
  PRIO0; BAR;                                                                 \
  READA(a1, CUR, 1);                                                          \
  if ((T)+2 < nt) { STAGE_A(CUR, 0, ((T)+2) << 6);                            \
                    STAGE_B(CUR, 0, ((T)+2) << 6);                            \
                    STAGE_B(CUR, 1, ((T)+2) << 6); }                          \
  BAR; PRIO1;                                                                 \
  MFMA16(1, 1, a1, b1); MFMA16(1, 0, a1, b0);                                 \
  PRIO0;                                                                      \
  if ((T)+2 < nt) { VMC(6); } else { VMC(0); }                                \
  BAR; }

__global__ __launch_bounds__(512, 2) void k_down256(
    const u16* __restrict__ A, const u16* __restrict__ B0,
    const float* __restrict__ sc0, float* __restrict__ of32,
    int K, int NBN, int ldc)
{
    __shared__ __align__(16) u16 lds[65536];   // 128 KiB

    const int tid  = threadIdx.x;
    const int lane = tid & 63;
    const int wave = tid >> 6;
    const int wm   = wave >> 2;
    const int wn   = wave & 3;

    const int nwg  = 16 * NBN;
    const int orig = blockIdx.x;
    const int qq   = nwg >> 3, rr = nwg & 7;
    const int xcd  = orig & 7;
    const int swz  = (xcd < rr ? xcd*(qq+1) : rr*(qq+1) + (xcd-rr)*qq) + (orig >> 3);
    const int bm   = swz / NBN;
    const int bn   = swz % NBN;

    const int r    = lane & 15;
    const int sQ   = lane >> 4;
    const int x7   = r & 7;
    const int g0E  = (sQ ^ x7) * 8;
    const int g1E  = ((4 | sQ) ^ x7) * 8;
    const int aoffE = (wm*64 + r) * 64;
    const int boffE = (wn*32 + r) * 64;

    const int lrow = lane >> 3;
    const int goff = ((lane & 7) ^ lrow) * 8;
    const size_t a_sbase = (size_t)(bm*256 + wave*8 + lrow) * K + goff;
    const u16* b0base = B0 + (size_t)(bn*256 +       wave*8 + lrow) * K + goff;
    const u16* b1base = B0 + (size_t)(bn*256 + 128 + wave*8 + lrow) * K + goff;

    f32x4 acc[8][4];
#pragma unroll
    for (int m = 0; m < 8; ++m)
#pragma unroll
        for (int n = 0; n < 4; ++n) acc[m][n] = (f32x4){0.f, 0.f, 0.f, 0.f};

    const int nt = K >> 6;              // 172 for K=11008 (even)

    STAGE_A(0, 0, 0); STAGE_A(0, 1, 0); STAGE_B(0, 0, 0); STAGE_B(0, 1, 0);
    STAGE_A(1, 0, 64); STAGE_B(1, 0, 64); STAGE_B(1, 1, 64);
    VMC(6);
    BAR;

    bf16x8 a0[4][2], a1[4][2], b0[2][2], b1[2][2];
    for (int t = 0; t < nt; t += 2) {
        TILE2(0, 1, t);
        TILE2(1, 0, t + 1);
    }

#pragma unroll
    for (int n = 0; n < 4; ++n) {
        const int col = bn*256 + (n>>1)*128 + wn*32 + (n&1)*16 + r;
        const float sc = sc0[col];
#pragma unroll
        for (int m = 0; m < 8; ++m) {
            const int row = bm*256 + (m>>2)*128 + wm*64 + (m&3)*16 + sQ*4;
#pragma unroll
            for (int q = 0; q < 4; ++q)
                of32[(size_t)(row + q) * ldc + col] = acc[m][n][q] * sc;
        }
    }
}

extern "C" void kernel_launch(void* const* d_in, const int* in_sizes, int n_in,
                              void* d_out, int out_size, void* d_ws, size_t ws_size,
                              hipStream_t stream) {
    const float* x  = (const float*)d_in[0];
    const int*   gw = (const int*)d_in[1];
    const float* gs = (const float*)d_in[2];
    const int*   uw = (const int*)d_in[3];
    const float* us = (const float*)d_in[4];
    const int*   dw = (const int*)d_in[5];
    const float* ds = (const float*)d_in[6];
    float* out = (float*)d_out;

    const size_t XQ = (size_t)NTOK * D_MODEL;       // 16.8 MB  x s8
    const size_t W8 = (size_t)D_FF * D_MODEL;       // 45.1 MB  weight s8
    const size_t WD = (size_t)D_FF * D_MODEL * 2;   // 90.2 MB  down weight bf16
    const size_t HB = (size_t)NTOK * D_FF * 2;      // 90.2 MB  h bf16
    if (ws_size < XQ + 2 * W8 + WD + HB) return;    // loud failure (poisoned out)

    char* ws = (char*)d_ws;
    s8*  xq  = (s8*)ws;
    s8*  wg8 = (s8*)(ws + XQ);
    s8*  wu8 = (s8*)(ws + XQ + W8);
    u16* wbD = (u16*)(ws + XQ + 2 * W8);
    u16* hb  = (u16*)(ws + XQ + 2 * W8 + WD);

    const int wn_elems = D_FF * D_MODEL;            // 45,088,768
    const int wgrid = wn_elems / (8 * 256);

    k_quant_x<<<(NTOK * D_MODEL) / (8 * 256), 256, 0, stream>>>(x, xq);
    k_cvt_w8<<<wgrid, 256, 0, stream>>>(gw, wg8);
    k_cvt_w8<<<wgrid, 256, 0, stream>>>(uw, wu8);

    // fused i8: h = bf16( silu((xq.gw^T)*S*gs) * (xq.uw^T)*S*us )
    k_fusedgu_i8<<<16 * (D_FF / 128), 512, 0, stream>>>(
        xq, wg8, wu8, gs, us, hb, D_MODEL, D_FF / 128, D_FF);

    // down (bf16): out = (h . dw^T) * ds
    k_cvt_w<<<wgrid, 256, 0, stream>>>(dw, wbD);
    k_down256<<<16 * (D_MODEL / 256), 512, 0, stream>>>(
        hb, wbD, ds, out, D_FF, D_MODEL / 256, D_MODEL);
}

// Round 16
// 851.378 us; speedup vs baseline: 1.6921x; 1.0046x over previous
//
#include <hip/hip_runtime.h>
#include <hip/hip_bf16.h>

#define D_MODEL 4096
#define D_FF    11008
#define NTOK    4096   // 2 * 2048 tokens

typedef unsigned int u32;
typedef unsigned short u16;
typedef signed char s8;
using f32x4   = __attribute__((ext_vector_type(4))) float;
using i32x4   = __attribute__((ext_vector_type(4))) int;
using bf16x8  = __attribute__((ext_vector_type(8))) short;
using ushort8 = __attribute__((ext_vector_type(8))) unsigned short;
using u32x2   = __attribute__((ext_vector_type(2))) u32;
using int4v   = __attribute__((ext_vector_type(4))) int;
using float4v = __attribute__((ext_vector_type(4))) float;

__device__ __forceinline__ u16 bf16_rn(float f) {
    u32 u = __builtin_bit_cast(u32, f);
    u += 0x7FFFu + ((u >> 16) & 1u);
    return (u16)(u >> 16);
}
__device__ __forceinline__ u16 bf16_from_int(int v) {
    float f = (float)v;   // exact for |v| <= 127
    return (u16)(__builtin_bit_cast(u32, f) >> 16);
}
__device__ __forceinline__ void gload16(const void* g, void* l) {
    __builtin_amdgcn_global_load_lds(
        (const __attribute__((address_space(1))) u32*)g,
        (__attribute__((address_space(3))) u32*)l, 16, 0, 0);
}

// ---------------- per-token |x| max -> xsc[row] = max/127 ----------------
__global__ void k_xscale(const float* __restrict__ x, float* __restrict__ xsc) {
    __shared__ float wmax[4];
    const int row = blockIdx.x;
    const int tid = threadIdx.x;
    const float* p = x + (size_t)row * D_MODEL + tid * 16;
    float m = 0.f;
#pragma unroll
    for (int j = 0; j < 4; ++j) {
        float4v v = *(const float4v*)(p + j * 4);
#pragma unroll
        for (int e = 0; e < 4; ++e) m = fmaxf(m, fabsf(v[e]));
    }
#pragma unroll
    for (int off = 1; off < 64; off <<= 1)
        m = fmaxf(m, __shfl_xor(m, off));
    if ((tid & 63) == 0) wmax[tid >> 6] = m;
    __syncthreads();
    if (tid == 0) {
        m = fmaxf(fmaxf(wmax[0], wmax[1]), fmaxf(wmax[2], wmax[3]));
        xsc[row] = m * (1.0f / 127.0f);
    }
}

// ---------------- x fp32 -> s8 (per-token scale) ----------------
__global__ void k_quant_x(const float* __restrict__ x, const float* __restrict__ xsc,
                          s8* __restrict__ xq) {
    int i = (blockIdx.x * 256 + threadIdx.x) * 8;
    const float inv = 1.0f / xsc[i >> 12];          // 4096 elems/row
    float4v a = *(const float4v*)(x + i);
    float4v b = *(const float4v*)(x + i + 4);
    u32 w0 = 0, w1 = 0;
#pragma unroll
    for (int e = 0; e < 4; ++e) {
        int qa = (int)rintf(a[e] * inv);
        qa = qa > 127 ? 127 : (qa < -127 ? -127 : qa);
        int qb = (int)rintf(b[e] * inv);
        qb = qb > 127 ? 127 : (qb < -127 ? -127 : qb);
        w0 |= (u32)(qa & 255) << (8 * e);
        w1 |= (u32)(qb & 255) << (8 * e);
    }
    *(u32x2*)(xq + i) = (u32x2){w0, w1};
}

// ---------------- weight int32 -> s8 ----------------
__global__ void k_cvt_w8(const int* __restrict__ w, s8* __restrict__ wb) {
    int i = (blockIdx.x * 256 + threadIdx.x) * 8;
    int4v a = *(const int4v*)(w + i);
    int4v b = *(const int4v*)(w + i + 4);
    u32 w0 = 0, w1 = 0;
#pragma unroll
    for (int e = 0; e < 4; ++e) {
        w0 |= (u32)(a[e] & 255) << (8 * e);
        w1 |= (u32)(b[e] & 255) << (8 * e);
    }
    *(u32x2*)(wb + i) = (u32x2){w0, w1};
}

// ---------------- weight int32 -> bf16 (for down GEMM) ----------------
__global__ void k_cvt_w(const int* __restrict__ w, u16* __restrict__ wb) {
    int i = (blockIdx.x * 256 + threadIdx.x) * 8;
    int4v a = *(const int4v*)(w + i);
    int4v b = *(const int4v*)(w + i + 4);
    ushort8 o;
    o[0] = bf16_from_int(a[0]); o[1] = bf16_from_int(a[1]);
    o[2] = bf16_from_int(a[2]); o[3] = bf16_from_int(a[3]);
    o[4] = bf16_from_int(b[0]); o[5] = bf16_from_int(b[1]);
    o[6] = bf16_from_int(b[2]); o[7] = bf16_from_int(b[3]);
    *(ushort8*)(wb + i) = o;
}

// =====================================================================
// FUSED gate+up GEMM, INT8: 256 tokens x 128 f-cols, BK=64,
// mfma_i32_16x16x64_i8, 64 KiB LDS dbuf, R12-proven 2-phase schedule
// (vmcnt(3) gate for 4 gloads/tile/wave).
// Conflict-free swizzle (R15 fix, kept): granule position p of row R
// holds k-granule p ^ ((R>>1)&3) -> (r&7) <-> (row&1, granule)
// bijection on reads = 2-way only (free). Stage-side inverse:
// (lane&3)^((lane>>3)&3).
// Epilogue: h = bf16( silu(acc_g*xsc[row]*gs) * acc_u*xsc[row]*us ).
// =====================================================================

#define BAR   __builtin_amdgcn_s_barrier()
#define PRIO1 __builtin_amdgcn_s_setprio(1)
#define PRIO0 __builtin_amdgcn_s_setprio(0)
#define VMC(N)  asm volatile("s_waitcnt vmcnt(" #N ")" ::: "memory")

#define RD_A8(AA, BUF, MH) {                                                  \
  _Pragma("unroll") for (int mm = 0; mm < 4; ++mm)                            \
    AA[mm] = *(const i32x4*)&lds8[(BUF)*32768 + (MH)*8192 + mm*1024 + adA]; }

#define RD_B8(BB, BUF) {                                                      \
  _Pragma("unroll") for (int nn = 0; nn < 4; ++nn)                            \
    BB[nn] = *(const i32x4*)&lds8[(BUF)*32768 + 16384 + (nn>>1)*8192 +        \
                                  (nn&1)*1024 + adB]; }

#define MFMA_I8(MH, AA, BB)                                                   \
  _Pragma("unroll") for (int mm = 0; mm < 4; ++mm)                            \
  _Pragma("unroll") for (int nn = 0; nn < 4; ++nn)                            \
    acc[(MH)*4+mm][nn] = __builtin_amdgcn_mfma_i32_16x16x64_i8(               \
        AA[mm], BB[nn], acc[(MH)*4+mm][nn], 0, 0, 0);

#define STAGE_AH(BUF, MH, K0) {                                               \
  gload16(xq + (size_t)(bm*256 + (MH)*128 + wave*16 + (lane>>2))*K + (K0) + asw, \
          &lds8[(BUF)*32768 + (MH)*8192 + wave*1024 + lane*16]); }

#define STAGE_B2(BUF, K0) {                                                   \
  gload16(b0base + (size_t)(wave*16 + (lane>>2))*K + (K0) + asw,              \
          &lds8[(BUF)*32768 + 16384 + wave*1024 + lane*16]);                  \
  gload16(b1base + (size_t)(wave*16 + (lane>>2))*K + (K0) + asw,              \
          &lds8[(BUF)*32768 + 24576 + wave*1024 + lane*16]); }

#define TILE_I8(CUR, NXT, T) {                                                \
  RD_A8(a0, CUR, 0); RD_B8(bb, CUR);                                          \
  if ((T)+1 < nt) STAGE_AH(NXT, 1, ((T)+1) << 6);                             \
  BAR; PRIO1; MFMA_I8(0, a0, bb); PRIO0; BAR;                                 \
  RD_A8(a1, CUR, 1);                                                          \
  if ((T)+2 < nt) { STAGE_AH(CUR, 0, ((T)+2) << 6);                           \
                    STAGE_B2(CUR, ((T)+2) << 6); }                            \
  BAR; PRIO1; MFMA_I8(1, a1, bb); PRIO0;                                      \
  if ((T)+2 < nt) { VMC(3); } else { VMC(0); }                                \
  BAR; }

__global__ __launch_bounds__(512, 2) void k_fusedgu_i8(
    const s8* __restrict__ xq,
    const s8* __restrict__ wg8, const s8* __restrict__ wu8,
    const float* __restrict__ gs, const float* __restrict__ us,
    const float* __restrict__ xsc,
    u16* __restrict__ hb, int K, int NBN, int ldc)
{
    __shared__ __align__(16) char lds8[65536];   // 64 KiB

    const int tid  = threadIdx.x;
    const int lane = tid & 63;
    const int wave = tid >> 6;          // 0..7
    const int wm   = wave >> 2;         // 0..1
    const int wn   = wave & 3;          // 0..3

    // XCD-aware bijective swizzle; bm slow, bn fast
    const int nwg  = 16 * NBN;
    const int orig = blockIdx.x;
    const int qq   = nwg >> 3, rr = nwg & 7;
    const int xcd  = orig & 7;
    const int swz  = (xcd < rr ? xcd*(qq+1) : rr*(qq+1) + (xcd-rr)*qq) + (orig >> 3);
    const int bm   = swz / NBN;
    const int bn   = swz % NBN;

    // fragment-read constants (bytes) — conflict-free swizzle
    const int r    = lane & 15;
    const int sQ   = lane >> 4;                        // k-granule 0..3
    const int qsw  = (sQ ^ ((r >> 1) & 3)) * 16;       // swizzled granule
    const int adA  = (wm*64 + r) * 64 + qsw;
    const int adB  = (wn*32 + r) * 64 + qsw;

    // stage source swizzle (inverse involution)
    const int asw  = ((lane & 3) ^ ((lane >> 3) & 3)) * 16;

    const s8* b0base = wg8 + (size_t)(bn*128) * K;
    const s8* b1base = wu8 + (size_t)(bn*128) * K;

    i32x4 acc[8][4];
#pragma unroll
    for (int m = 0; m < 8; ++m)
#pragma unroll
        for (int n = 0; n < 4; ++n) acc[m][n] = (i32x4){0, 0, 0, 0};

    const int nt = K >> 6;              // 64 for K=4096 (even)

    // prologue: tile0 fully [4 gloads], tile1 {Ah0, B} [3]
    STAGE_AH(0, 0, 0); STAGE_AH(0, 1, 0); STAGE_B2(0, 0);
    STAGE_AH(1, 0, 64); STAGE_B2(1, 64);
    VMC(3);
    BAR;

    i32x4 a0[4], a1[4], bb[4];
    for (int t = 0; t < nt; t += 2) {
        TILE_I8(0, 1, t);
        TILE_I8(1, 0, t + 1);
    }

    // epilogue: n=0,1 -> gate; n=2,3 -> up (same f-cols)
    const int f0 = bn*128 + wn*32 + r;
    const float gsc0 = gs[f0],      usc0 = us[f0];
    const float gsc1 = gs[f0 + 16], usc1 = us[f0 + 16];
#pragma unroll
    for (int m = 0; m < 8; ++m) {
        const int row = bm*256 + (m>>2)*128 + wm*64 + (m&3)*16 + sQ*4;
#pragma unroll
        for (int q = 0; q < 4; ++q) {
            const float xs = xsc[row + q];
            const float g0 = (float)acc[m][0][q] * xs * gsc0;
            const float u0 = (float)acc[m][2][q] * xs * usc0;
            const float g1 = (float)acc[m][1][q] * xs * gsc1;
            const float u1 = (float)acc[m][3][q] * xs * usc1;
            const float h0 = (g0 / (1.0f + __expf(-g0))) * u0;
            const float h1 = (g1 / (1.0f + __expf(-g1))) * u1;
            hb[(size_t)(row + q) * ldc + f0]      = bf16_rn(h0);
            hb[(size_t)(row + q) * ldc + f0 + 16] = bf16_rn(h1);
        }
    }
}

// =====================================================================
// DOWN GEMM (bf16) — exact R12 structure (proven): 256x256, 2-phase,
// vmcnt(6), XOR-granule swizzle, gload_lds staging, setprio.
// out[m,d] = (h . dw^T)[m,d] * ds[d]   (fp32 out)
// =====================================================================

#define READA(AA, BUF, MH) {                                                  \
  _Pragma("unroll") for (int mm = 0; mm < 4; ++mm) {                          \
    AA[mm][0] = *(const bf16x8*)&lds[(BUF)*32768 + (MH)*8192 + mm*1024 + aoffE + g0E]; \
    AA[mm][1] = *(const bf16x8*)&lds[(BUF)*32768 + (MH)*8192 + mm*1024 + aoffE + g1E]; } }

#define READB(BB, BUF, NH) {                                                  \
  _Pragma("unroll") for (int nn = 0; nn < 2; ++nn) {                          \
    BB[nn][0] = *(const bf16x8*)&lds[(BUF)*32768 + 16384 + (NH)*8192 + nn*1024 + boffE + g0E]; \
    BB[nn][1] = *(const bf16x8*)&lds[(BUF)*32768 + 16384 + (NH)*8192 + nn*1024 + boffE + g1E]; } }

#define MFMA16(MH, NH, AA, BB)                                                \
  _Pragma("unroll") for (int mm = 0; mm < 4; ++mm)                            \
  _Pragma("unroll") for (int nn = 0; nn < 2; ++nn)                            \
  _Pragma("unroll") for (int kk = 0; kk < 2; ++kk)                            \
    acc[(MH)*4+mm][(NH)*2+nn] = __builtin_amdgcn_mfma_f32_16x16x32_bf16(      \
        AA[mm][kk], BB[nn][kk], acc[(MH)*4+mm][(NH)*2+nn], 0, 0, 0);

#define REGA(BUF, H) ((BUF)*32768 + (H)*8192)
#define REGB(BUF, H) ((BUF)*32768 + 16384 + (H)*8192)

#define STAGE_A(BUF, MH, K0) {                                                \
  const u16* _s = A + a_sbase + (size_t)(MH)*128*K + (K0);                    \
  gload16(_s,                &lds[REGA(BUF, MH) + wave*512]);                 \
  gload16(_s + (size_t)64*K, &lds[REGA(BUF, MH) + (8+wave)*512]); }

#define STAGE_B(BUF, NH, K0) {                                                \
  const u16* _s = ((NH) ? b1base : b0base) + (K0);                            \
  gload16(_s,                &lds[REGB(BUF, NH) + wave*512]);                 \
  gload16(_s + (size_t)64*K, &lds[REGB(BUF, NH) + (8+wave)*512]); }

#define TILE2(CUR, NXT, T) {                                                  \
  READA(a0, CUR, 0); READB(b0, CUR, 0); READB(b1, CUR, 1);                    \
  if ((T)+1 < nt) STAGE_A(NXT, 1, ((T)+1) << 6);                              \
  BAR; PRIO1;                                                                 \
  MFMA16(0, 0, a0, b0); MFMA16(0, 1, a0, b1);                                 \
  PRIO0; BAR;                                                                 \
  READA(a1, CUR, 1);                                                          \
  if ((T)+2 < nt) { STAGE_A(CUR, 0, ((T)+2) << 6);                            \
                    STAGE_B(CUR, 0, ((T)+2) << 6);                            \
                    STAGE_B(CUR, 1, ((T)+2) << 6); }                          \
  BAR; PRIO1;                                                                 \
  MFMA16(1, 1, a1, b1); MFMA16(1, 0, a1, b0);                                 \
  PRIO0;                                                                      \
  if ((T)+2 < nt) { VMC(6); } else { VMC(0); }                                \
  BAR; }

__global__ __launch_bounds__(512, 2) void k_down256(
    const u16* __restrict__ A, const u16* __restrict__ B0,
    const float* __restrict__ sc0, float* __restrict__ of32,
    int K, int NBN, int ldc)
{
    __shared__ __align__(16) u16 lds[65536];   // 128 KiB

    const int tid  = threadIdx.x;
    const int lane = tid & 63;
    const int wave = tid >> 6;
    const int wm   = wave >> 2;
    const int wn   = wave & 3;

    const int nwg  = 16 * NBN;
    const int orig = blockIdx.x;
    const int qq   = nwg >> 3, rr = nwg & 7;
    const int xcd  = orig & 7;
    const int swz  = (xcd < rr ? xcd*(qq+1) : rr*(qq+1) + (xcd-rr)*qq) + (orig >> 3);
    const int bm   = swz / NBN;
    const int bn   = swz % NBN;

    const int r    = lane & 15;
    const int sQ   = lane >> 4;
    const int x7   = r & 7;
    const int g0E  = (sQ ^ x7) * 8;
    const int g1E  = ((4 | sQ) ^ x7) * 8;
    const int aoffE = (wm*64 + r) * 64;
    const int boffE = (wn*32 + r) * 64;

    const int lrow = lane >> 3;
    const int goff = ((lane & 7) ^ lrow) * 8;
    const size_t a_sbase = (size_t)(bm*256 + wave*8 + lrow) * K + goff;
    const u16* b0base = B0 + (size_t)(bn*256 +       wave*8 + lrow) * K + goff;
    const u16* b1base = B0 + (size_t)(bn*256 + 128 + wave*8 + lrow) * K + goff;

    f32x4 acc[8][4];
#pragma unroll
    for (int m = 0; m < 8; ++m)
#pragma unroll
        for (int n = 0; n < 4; ++n) acc[m][n] = (f32x4){0.f, 0.f, 0.f, 0.f};

    const int nt = K >> 6;              // 172 for K=11008 (even)

    STAGE_A(0, 0, 0); STAGE_A(0, 1, 0); STAGE_B(0, 0, 0); STAGE_B(0, 1, 0);
    STAGE_A(1, 0, 64); STAGE_B(1, 0, 64); STAGE_B(1, 1, 64);
    VMC(6);
    BAR;

    bf16x8 a0[4][2], a1[4][2], b0[2][2], b1[2][2];
    for (int t = 0; t < nt; t += 2) {
        TILE2(0, 1, t);
        TILE2(1, 0, t + 1);
    }

#pragma unroll
    for (int n = 0; n < 4; ++n) {
        const int col = bn*256 + (n>>1)*128 + wn*32 + (n&1)*16 + r;
        const float sc = sc0[col];
#pragma unroll
        for (int m = 0; m < 8; ++m) {
            const int row = bm*256 + (m>>2)*128 + wm*64 + (m&3)*16 + sQ*4;
#pragma unroll
            for (int q = 0; q < 4; ++q)
                of32[(size_t)(row + q) * ldc + col] = acc[m][n][q] * sc;
        }
    }
}

extern "C" void kernel_launch(void* const* d_in, const int* in_sizes, int n_in,
                              void* d_out, int out_size, void* d_ws, size_t ws_size,
                              hipStream_t stream) {
    const float* x  = (const float*)d_in[0];
    const int*   gw = (const int*)d_in[1];
    const float* gs = (const float*)d_in[2];
    const int*   uw = (const int*)d_in[3];
    const float* us = (const float*)d_in[4];
    const int*   dw = (const int*)d_in[5];
    const float* ds = (const float*)d_in[6];
    float* out = (float*)d_out;

    const size_t XQ = (size_t)NTOK * D_MODEL;       // 16.8 MB  x s8
    const size_t W8 = (size_t)D_FF * D_MODEL;       // 45.1 MB  weight s8
    const size_t WD = (size_t)D_FF * D_MODEL * 2;   // 90.2 MB  down weight bf16
    const size_t HB = (size_t)NTOK * D_FF * 2;      // 90.2 MB  h bf16
    const size_t SC = (size_t)NTOK * 4;             // 16 KB    per-token x scale
    if (ws_size < XQ + 2 * W8 + WD + HB + SC) return;  // loud failure

    char* ws = (char*)d_ws;
    s8*  xq   = (s8*)ws;
    s8*  wg8  = (s8*)(ws + XQ);
    s8*  wu8  = (s8*)(ws + XQ + W8);
    u16* wbD  = (u16*)(ws + XQ + 2 * W8);
    u16* hb   = (u16*)(ws + XQ + 2 * W8 + WD);
    float* xsc = (float*)(ws + XQ + 2 * W8 + WD + HB);

    const int wn_elems = D_FF * D_MODEL;            // 45,088,768
    const int wgrid = wn_elems / (8 * 256);

    k_xscale<<<NTOK, 256, 0, stream>>>(x, xsc);
    k_quant_x<<<(NTOK * D_MODEL) / (8 * 256), 256, 0, stream>>>(x, xsc, xq);
    k_cvt_w8<<<wgrid, 256, 0, stream>>>(gw, wg8);
    k_cvt_w8<<<wgrid, 256, 0, stream>>>(uw, wu8);

    // fused i8: h = bf16( silu((xq.gw^T)*xs*gs) * (xq.uw^T)*xs*us )
    k_fusedgu_i8<<<16 * (D_FF / 128), 512, 0, stream>>>(
        xq, wg8, wu8, gs, us, xsc, hb, D_MODEL, D_FF / 128, D_FF);

    // down (bf16): out = (h . dw^T) * ds
    k_cvt_w<<<wgrid, 256, 0, stream>>>(dw, wbD);
    k_down256<<<16 * (D_MODEL / 256), 512, 0, stream>>>(
        hb, wbD, ds, out, D_FF, D_MODEL / 256, D_MODEL);
}

// Round 17
// 817.463 us; speedup vs baseline: 1.7623x; 1.0415x over previous
//
#include <hip/hip_runtime.h>
#include <hip/hip_bf16.h>

#define D_MODEL 4096
#define D_FF    11008
#define NTOK    4096   // 2 * 2048 tokens
#define CVT_BLOCKS 2048

typedef unsigned int u32;
typedef unsigned short u16;
typedef signed char s8;
using f32x4   = __attribute__((ext_vector_type(4))) float;
using i32x4   = __attribute__((ext_vector_type(4))) int;
using bf16x8  = __attribute__((ext_vector_type(8))) short;
using ushort8 = __attribute__((ext_vector_type(8))) unsigned short;
using u32x2   = __attribute__((ext_vector_type(2))) u32;
using int4v   = __attribute__((ext_vector_type(4))) int;
using float4v = __attribute__((ext_vector_type(4))) float;

__device__ __forceinline__ u16 bf16_rn(float f) {
    u32 u = __builtin_bit_cast(u32, f);
    u += 0x7FFFu + ((u >> 16) & 1u);
    return (u16)(u >> 16);
}
__device__ __forceinline__ u16 bf16_from_int(int v) {
    float f = (float)v;   // exact for |v| <= 127
    return (u16)(__builtin_bit_cast(u32, f) >> 16);
}
__device__ __forceinline__ void gload16(const void* g, void* l) {
    __builtin_amdgcn_global_load_lds(
        (const __attribute__((address_space(1))) u32*)g,
        (__attribute__((address_space(3))) u32*)l, 16, 0, 0);
}

// ---------------- single-pass x: per-token max + quantize ----------------
__global__ void k_prep_x(const float* __restrict__ x, s8* __restrict__ xq,
                         float* __restrict__ xsc) {
    __shared__ float wmax[4];
    const int row = blockIdx.x;
    const int tid = threadIdx.x;
    const float* p = x + (size_t)row * D_MODEL + tid * 16;
    float4v v0 = *(const float4v*)(p);
    float4v v1 = *(const float4v*)(p + 4);
    float4v v2 = *(const float4v*)(p + 8);
    float4v v3 = *(const float4v*)(p + 12);
    float m = 0.f;
#pragma unroll
    for (int e = 0; e < 4; ++e)
        m = fmaxf(m, fmaxf(fmaxf(fabsf(v0[e]), fabsf(v1[e])),
                           fmaxf(fabsf(v2[e]), fabsf(v3[e]))));
#pragma unroll
    for (int off = 1; off < 64; off <<= 1)
        m = fmaxf(m, __shfl_xor(m, off));
    if ((tid & 63) == 0) wmax[tid >> 6] = m;
    __syncthreads();
    m = fmaxf(fmaxf(wmax[0], wmax[1]), fmaxf(wmax[2], wmax[3]));
    if (tid == 0) xsc[row] = m * (1.0f / 127.0f);
    const float inv = (m > 0.f) ? (127.0f / m) : 0.f;
    i32x4 o;
    float4v vs[4] = {v0, v1, v2, v3};
#pragma unroll
    for (int j = 0; j < 4; ++j) {
        u32 w = 0;
#pragma unroll
        for (int e = 0; e < 4; ++e) {
            int q = (int)rintf(vs[j][e] * inv);
            q = q > 127 ? 127 : (q < -127 ? -127 : q);
            w |= (u32)(q & 255) << (8 * e);
        }
        o[j] = (int)w;
    }
    *(i32x4*)(xq + (size_t)row * D_MODEL + tid * 16) = o;
}

// ---------------- dual weight int32 -> s8 (gate + up in one launch) -----
__global__ void k_cvt_w8x2(const int* __restrict__ wA, const int* __restrict__ wB,
                           s8* __restrict__ oA, s8* __restrict__ oB, int halfgrid) {
    const int b = blockIdx.x;
    const int* w; s8* o; int bb;
    if (b < halfgrid) { w = wA; o = oA; bb = b; }
    else              { w = wB; o = oB; bb = b - halfgrid; }
    int i = (bb * 256 + threadIdx.x) * 8;
    int4v a = *(const int4v*)(w + i);
    int4v c = *(const int4v*)(w + i + 4);
    u32 w0 = 0, w1 = 0;
#pragma unroll
    for (int e = 0; e < 4; ++e) {
        w0 |= (u32)(a[e] & 255) << (8 * e);
        w1 |= (u32)(c[e] & 255) << (8 * e);
    }
    *(u32x2*)(o + i) = (u32x2){w0, w1};
}

// =====================================================================
// FUSED gate+up GEMM, INT8 (R16-proven, untouched GEMM path) + TAIL
// BLOCKS (blockIdx >= nwgemm) that convert dw int32 -> bf16 for the
// down GEMM. dw is not read until the down GEMM (stream-ordered after
// this launch completes); tail blocks share no outputs with GEMM
// blocks -> race-free. The GEMM uses ~25% of HBM; the conversion's
// 270 MB rides in the spare bandwidth.
// GEMM: 256 tokens x 128 f-cols, BK=64, mfma_i32_16x16x64_i8,
// 64 KiB LDS dbuf, 2-phase schedule, vmcnt(3) gate, conflict-free
// swizzle (granule p of row R holds p^((R>>1)&3); stage inverse
// (lane&3)^((lane>>3)&3)).
// Epilogue: h = bf16( silu(acc_g*xsc[row]*gs) * acc_u*xsc[row]*us ).
// =====================================================================

#define BAR   __builtin_amdgcn_s_barrier()
#define PRIO1 __builtin_amdgcn_s_setprio(1)
#define PRIO0 __builtin_amdgcn_s_setprio(0)
#define VMC(N)  asm volatile("s_waitcnt vmcnt(" #N ")" ::: "memory")

#define RD_A8(AA, BUF, MH) {                                                  \
  _Pragma("unroll") for (int mm = 0; mm < 4; ++mm)                            \
    AA[mm] = *(const i32x4*)&lds8[(BUF)*32768 + (MH)*8192 + mm*1024 + adA]; }

#define RD_B8(BB, BUF) {                                                      \
  _Pragma("unroll") for (int nn = 0; nn < 4; ++nn)                            \
    BB[nn] = *(const i32x4*)&lds8[(BUF)*32768 + 16384 + (nn>>1)*8192 +        \
                                  (nn&1)*1024 + adB]; }

#define MFMA_I8(MH, AA, BB)                                                   \
  _Pragma("unroll") for (int mm = 0; mm < 4; ++mm)                            \
  _Pragma("unroll") for (int nn = 0; nn < 4; ++nn)                            \
    acc[(MH)*4+mm][nn] = __builtin_amdgcn_mfma_i32_16x16x64_i8(               \
        AA[mm], BB[nn], acc[(MH)*4+mm][nn], 0, 0, 0);

#define STAGE_AH(BUF, MH, K0) {                                               \
  gload16(xq + (size_t)(bm*256 + (MH)*128 + wave*16 + (lane>>2))*K + (K0) + asw, \
          &lds8[(BUF)*32768 + (MH)*8192 + wave*1024 + lane*16]); }

#define STAGE_B2(BUF, K0) {                                                   \
  gload16(b0base + (size_t)(wave*16 + (lane>>2))*K + (K0) + asw,              \
          &lds8[(BUF)*32768 + 16384 + wave*1024 + lane*16]);                  \
  gload16(b1base + (size_t)(wave*16 + (lane>>2))*K + (K0) + asw,              \
          &lds8[(BUF)*32768 + 24576 + wave*1024 + lane*16]); }

#define TILE_I8(CUR, NXT, T) {                                                \
  RD_A8(a0, CUR, 0); RD_B8(bb, CUR);                                          \
  if ((T)+1 < nt) STAGE_AH(NXT, 1, ((T)+1) << 6);                             \
  BAR; PRIO1; MFMA_I8(0, a0, bb); PRIO0; BAR;                                 \
  RD_A8(a1, CUR, 1);                                                          \
  if ((T)+2 < nt) { STAGE_AH(CUR, 0, ((T)+2) << 6);                           \
                    STAGE_B2(CUR, ((T)+2) << 6); }                            \
  BAR; PRIO1; MFMA_I8(1, a1, bb); PRIO0;                                      \
  if ((T)+2 < nt) { VMC(3); } else { VMC(0); }                                \
  BAR; }

__global__ __launch_bounds__(512, 2) void k_fusedgu_i8(
    const s8* __restrict__ xq,
    const s8* __restrict__ wg8, const s8* __restrict__ wu8,
    const float* __restrict__ gs, const float* __restrict__ us,
    const float* __restrict__ xsc,
    u16* __restrict__ hb, int K, int NBN, int ldc,
    const int* __restrict__ dw, u16* __restrict__ wbD, int nwgemm)
{
    __shared__ __align__(16) char lds8[65536];   // 64 KiB

    // ---- tail blocks: dw int32 -> bf16 (grid-stride, race-free) ----
    if ((int)blockIdx.x >= nwgemm) {
        const long long tidg = (long long)(blockIdx.x - nwgemm) * 512 + threadIdx.x;
        const long long stride = (long long)CVT_BLOCKS * 512 * 8;
        const long long n = (long long)D_FF * D_MODEL;
        for (long long i = tidg * 8; i < n; i += stride) {
            int4v a = *(const int4v*)(dw + i);
            int4v b = *(const int4v*)(dw + i + 4);
            ushort8 o;
            o[0] = bf16_from_int(a[0]); o[1] = bf16_from_int(a[1]);
            o[2] = bf16_from_int(a[2]); o[3] = bf16_from_int(a[3]);
            o[4] = bf16_from_int(b[0]); o[5] = bf16_from_int(b[1]);
            o[6] = bf16_from_int(b[2]); o[7] = bf16_from_int(b[3]);
            *(ushort8*)(wbD + i) = o;
        }
        return;
    }

    const int tid  = threadIdx.x;
    const int lane = tid & 63;
    const int wave = tid >> 6;          // 0..7
    const int wm   = wave >> 2;         // 0..1
    const int wn   = wave & 3;          // 0..3

    // XCD-aware bijective swizzle; bm slow, bn fast
    const int nwg  = 16 * NBN;
    const int orig = blockIdx.x;
    const int qq   = nwg >> 3, rr = nwg & 7;
    const int xcd  = orig & 7;
    const int swz  = (xcd < rr ? xcd*(qq+1) : rr*(qq+1) + (xcd-rr)*qq) + (orig >> 3);
    const int bm   = swz / NBN;
    const int bn   = swz % NBN;

    // fragment-read constants (bytes) — conflict-free swizzle
    const int r    = lane & 15;
    const int sQ   = lane >> 4;                        // k-granule 0..3
    const int qsw  = (sQ ^ ((r >> 1) & 3)) * 16;       // swizzled granule
    const int adA  = (wm*64 + r) * 64 + qsw;
    const int adB  = (wn*32 + r) * 64 + qsw;

    // stage source swizzle (inverse involution)
    const int asw  = ((lane & 3) ^ ((lane >> 3) & 3)) * 16;

    const s8* b0base = wg8 + (size_t)(bn*128) * K;
    const s8* b1base = wu8 + (size_t)(bn*128) * K;

    i32x4 acc[8][4];
#pragma unroll
    for (int m = 0; m < 8; ++m)
#pragma unroll
        for (int n = 0; n < 4; ++n) acc[m][n] = (i32x4){0, 0, 0, 0};

    const int nt = K >> 6;              // 64 for K=4096 (even)

    // prologue: tile0 fully [4 gloads], tile1 {Ah0, B} [3]
    STAGE_AH(0, 0, 0); STAGE_AH(0, 1, 0); STAGE_B2(0, 0);
    STAGE_AH(1, 0, 64); STAGE_B2(1, 64);
    VMC(3);
    BAR;

    i32x4 a0[4], a1[4], bb[4];
    for (int t = 0; t < nt; t += 2) {
        TILE_I8(0, 1, t);
        TILE_I8(1, 0, t + 1);
    }

    // epilogue: n=0,1 -> gate; n=2,3 -> up (same f-cols)
    const int f0 = bn*128 + wn*32 + r;
    const float gsc0 = gs[f0],      usc0 = us[f0];
    const float gsc1 = gs[f0 + 16], usc1 = us[f0 + 16];
#pragma unroll
    for (int m = 0; m < 8; ++m) {
        const int row = bm*256 + (m>>2)*128 + wm*64 + (m&3)*16 + sQ*4;
#pragma unroll
        for (int q = 0; q < 4; ++q) {
            const float xs = xsc[row + q];
            const float g0 = (float)acc[m][0][q] * xs * gsc0;
            const float u0 = (float)acc[m][2][q] * xs * usc0;
            const float g1 = (float)acc[m][1][q] * xs * gsc1;
            const float u1 = (float)acc[m][3][q] * xs * usc1;
            const float h0 = (g0 / (1.0f + __expf(-g0))) * u0;
            const float h1 = (g1 / (1.0f + __expf(-g1))) * u1;
            hb[(size_t)(row + q) * ldc + f0]      = bf16_rn(h0);
            hb[(size_t)(row + q) * ldc + f0 + 16] = bf16_rn(h1);
        }
    }
}

// =====================================================================
// DOWN GEMM (bf16) — exact R12 structure (proven): 256x256, 2-phase,
// vmcnt(6), XOR-granule swizzle, gload_lds staging, setprio.
// out[m,d] = (h . dw^T)[m,d] * ds[d]   (fp32 out)
// =====================================================================

#define READA(AA, BUF, MH) {                                                  \
  _Pragma("unroll") for (int mm = 0; mm < 4; ++mm) {                          \
    AA[mm][0] = *(const bf16x8*)&lds[(BUF)*32768 + (MH)*8192 + mm*1024 + aoffE + g0E]; \
    AA[mm][1] = *(const bf16x8*)&lds[(BUF)*32768 + (MH)*8192 + mm*1024 + aoffE + g1E]; } }

#define READB(BB, BUF, NH) {                                                  \
  _Pragma("unroll") for (int nn = 0; nn < 2; ++nn) {                          \
    BB[nn][0] = *(const bf16x8*)&lds[(BUF)*32768 + 16384 + (NH)*8192 + nn*1024 + boffE + g0E]; \
    BB[nn][1] = *(const bf16x8*)&lds[(BUF)*32768 + 16384 + (NH)*8192 + nn*1024 + boffE + g1E]; } }

#define MFMA16(MH, NH, AA, BB)                                                \
  _Pragma("unroll") for (int mm = 0; mm < 4; ++mm)                            \
  _Pragma("unroll") for (int nn = 0; nn < 2; ++nn)                            \
  _Pragma("unroll") for (int kk = 0; kk < 2; ++kk)                            \
    acc[(MH)*4+mm][(NH)*2+nn] = __builtin_amdgcn_mfma_f32_16x16x32_bf16(      \
        AA[mm][kk], BB[nn][kk], acc[(MH)*4+mm][(NH)*2+nn], 0, 0, 0);

#define REGA(BUF, H) ((BUF)*32768 + (H)*8192)
#define REGB(BUF, H) ((BUF)*32768 + 16384 + (H)*8192)

#define STAGE_A(BUF, MH, K0) {                                                \
  const u16* _s = A + a_sbase + (size_t)(MH)*128*K + (K0);                    \
  gload16(_s,                &lds[REGA(BUF, MH) + wave*512]);                 \
  gload16(_s + (size_t)64*K, &lds[REGA(BUF, MH) + (8+wave)*512]); }

#define STAGE_B(BUF, NH, K0) {                                                \
  const u16* _s = ((NH) ? b1base : b0base) + (K0);                            \
  gload16(_s,                &lds[REGB(BUF, NH) + wave*512]);                 \
  gload16(_s + (size_t)64*K, &lds[REGB(BUF, NH) + (8+wave)*512]); }

#define TILE2(CUR, NXT, T) {                                                  \
  READA(a0, CUR, 0); READB(b0, CUR, 0); READB(b1, CUR, 1);                    \
  if ((T)+1 < nt) STAGE_A(NXT, 1, ((T)+1) << 6);                              \
  BAR; PRIO1;                                                                 \
  MFMA16(0, 0, a0, b0); MFMA16(0, 1, a0, b1);                                 \
  PRIO0; BAR;                                                                 \
  READA(a1, CUR, 1);                                                          \
  if ((T)+2 < nt) { STAGE_A(CUR, 0, ((T)+2) << 6);                            \
                    STAGE_B(CUR, 0, ((T)+2) << 6);                            \
                    STAGE_B(CUR, 1, ((T)+2) << 6); }                          \
  BAR; PRIO1;                                                                 \
  MFMA16(1, 1, a1, b1); MFMA16(1, 0, a1, b0);                                 \
  PRIO0;                                                                      \
  if ((T)+2 < nt) { VMC(6); } else { VMC(0); }                                \
  BAR; }

__global__ __launch_bounds__(512, 2) void k_down256(
    const u16* __restrict__ A, const u16* __restrict__ B0,
    const float* __restrict__ sc0, float* __restrict__ of32,
    int K, int NBN, int ldc)
{
    __shared__ __align__(16) u16 lds[65536];   // 128 KiB

    const int tid  = threadIdx.x;
    const int lane = tid & 63;
    const int wave = tid >> 6;
    const int wm   = wave >> 2;
    const int wn   = wave & 3;

    const int nwg  = 16 * NBN;
    const int orig = blockIdx.x;
    const int qq   = nwg >> 3, rr = nwg & 7;
    const int xcd  = orig & 7;
    const int swz  = (xcd < rr ? xcd*(qq+1) : rr*(qq+1) + (xcd-rr)*qq) + (orig >> 3);
    const int bm   = swz / NBN;
    const int bn   = swz % NBN;

    const int r    = lane & 15;
    const int sQ   = lane >> 4;
    const int x7   = r & 7;
    const int g0E  = (sQ ^ x7) * 8;
    const int g1E  = ((4 | sQ) ^ x7) * 8;
    const int aoffE = (wm*64 + r) * 64;
    const int boffE = (wn*32 + r) * 64;

    const int lrow = lane >> 3;
    const int goff = ((lane & 7) ^ lrow) * 8;
    const size_t a_sbase = (size_t)(bm*256 + wave*8 + lrow) * K + goff;
    const u16* b0base = B0 + (size_t)(bn*256 +       wave*8 + lrow) * K + goff;
    const u16* b1base = B0 + (size_t)(bn*256 + 128 + wave*8 + lrow) * K + goff;

    f32x4 acc[8][4];
#pragma unroll
    for (int m = 0; m < 8; ++m)
#pragma unroll
        for (int n = 0; n < 4; ++n) acc[m][n] = (f32x4){0.f, 0.f, 0.f, 0.f};

    const int nt = K >> 6;              // 172 for K=11008 (even)

    STAGE_A(0, 0, 0); STAGE_A(0, 1, 0); STAGE_B(0, 0, 0); STAGE_B(0, 1, 0);
    STAGE_A(1, 0, 64); STAGE_B(1, 0, 64); STAGE_B(1, 1, 64);
    VMC(6);
    BAR;

    bf16x8 a0[4][2], a1[4][2], b0[2][2], b1[2][2];
    for (int t = 0; t < nt; t += 2) {
        TILE2(0, 1, t);
        TILE2(1, 0, t + 1);
    }

#pragma unroll
    for (int n = 0; n < 4; ++n) {
        const int col = bn*256 + (n>>1)*128 + wn*32 + (n&1)*16 + r;
        const float sc = sc0[col];
#pragma unroll
        for (int m = 0; m < 8; ++m) {
            const int row = bm*256 + (m>>2)*128 + wm*64 + (m&3)*16 + sQ*4;
#pragma unroll
            for (int q = 0; q < 4; ++q)
                of32[(size_t)(row + q) * ldc + col] = acc[m][n][q] * sc;
        }
    }
}

extern "C" void kernel_launch(void* const* d_in, const int* in_sizes, int n_in,
                              void* d_out, int out_size, void* d_ws, size_t ws_size,
                              hipStream_t stream) {
    const float* x  = (const float*)d_in[0];
    const int*   gw = (const int*)d_in[1];
    const float* gs = (const float*)d_in[2];
    const int*   uw = (const int*)d_in[3];
    const float* us = (const float*)d_in[4];
    const int*   dw = (const int*)d_in[5];
    const float* ds = (const float*)d_in[6];
    float* out = (float*)d_out;

    const size_t XQ = (size_t)NTOK * D_MODEL;       // 16.8 MB  x s8
    const size_t W8 = (size_t)D_FF * D_MODEL;       // 45.1 MB  weight s8
    const size_t WD = (size_t)D_FF * D_MODEL * 2;   // 90.2 MB  down weight bf16
    const size_t HB = (size_t)NTOK * D_FF * 2;      // 90.2 MB  h bf16
    const size_t SC = (size_t)NTOK * 4;             // 16 KB    per-token x scale
    if (ws_size < XQ + 2 * W8 + WD + HB + SC) return;  // loud failure

    char* ws = (char*)d_ws;
    s8*  xq   = (s8*)ws;
    s8*  wg8  = (s8*)(ws + XQ);
    s8*  wu8  = (s8*)(ws + XQ + W8);
    u16* wbD  = (u16*)(ws + XQ + 2 * W8);
    u16* hb   = (u16*)(ws + XQ + 2 * W8 + WD);
    float* xsc = (float*)(ws + XQ + 2 * W8 + WD + HB);

    const int wn_elems = D_FF * D_MODEL;            // 45,088,768
    const int wgrid = wn_elems / (8 * 256);
    const int nwgemm = 16 * (D_FF / 128);           // 1376

    // x: per-token max + quantize, single pass
    k_prep_x<<<NTOK, 256, 0, stream>>>(x, xq, xsc);
    // gate + up weights -> s8, one launch
    k_cvt_w8x2<<<2 * wgrid, 256, 0, stream>>>(gw, uw, wg8, wu8, wgrid);

    // fused i8 GEMM + tail blocks converting dw -> bf16 in spare HBM BW
    k_fusedgu_i8<<<nwgemm + CVT_BLOCKS, 512, 0, stream>>>(
        xq, wg8, wu8, gs, us, xsc, hb, D_MODEL, D_FF / 128, D_FF,
        dw, wbD, nwgemm);

    // down (bf16): out = (h . dw^T) * ds
    k_down256<<<16 * (D_MODEL / 256), 512, 0, stream>>>(
        hb, wbD, ds, out, D_FF, D_MODEL / 256, D_MODEL);
}

// Round 18
// 813.826 us; speedup vs baseline: 1.7702x; 1.0045x over previous
//
#include <hip/hip_runtime.h>
#include <hip/hip_bf16.h>

#define D_MODEL 4096
#define D_FF    11008
#define NTOK    4096   // 2 * 2048 tokens
#define CVT_BLOCKS 2048

typedef unsigned int u32;
typedef unsigned short u16;
typedef signed char s8;
using f32x4   = __attribute__((ext_vector_type(4))) float;
using i32x4   = __attribute__((ext_vector_type(4))) int;
using bf16x8  = __attribute__((ext_vector_type(8))) short;
using ushort8 = __attribute__((ext_vector_type(8))) unsigned short;
using u32x2   = __attribute__((ext_vector_type(2))) u32;
using int4v   = __attribute__((ext_vector_type(4))) int;
using float4v = __attribute__((ext_vector_type(4))) float;

__device__ __forceinline__ u16 bf16_rn(float f) {
    u32 u = __builtin_bit_cast(u32, f);
    u += 0x7FFFu + ((u >> 16) & 1u);
    return (u16)(u >> 16);
}
__device__ __forceinline__ u16 bf16_from_int(int v) {
    float f = (float)v;   // exact for |v| <= 127
    return (u16)(__builtin_bit_cast(u32, f) >> 16);
}
__device__ __forceinline__ void gload16(const void* g, void* l) {
    __builtin_amdgcn_global_load_lds(
        (const __attribute__((address_space(1))) u32*)g,
        (__attribute__((address_space(3))) u32*)l, 16, 0, 0);
}

// =====================================================================
// MERGED prep: blocks [0, NTOK)           -> per-token x max + quantize
//              blocks [NTOK, NTOK+2*wgrid) -> gate/up weights int32->s8
// All independent, 256 threads, BW-bound -> one launch.
// =====================================================================
__global__ void k_prep(const float* __restrict__ x, s8* __restrict__ xq,
                       float* __restrict__ xsc,
                       const int* __restrict__ gw, const int* __restrict__ uw,
                       s8* __restrict__ wg8, s8* __restrict__ wu8, int wgrid) {
    const int b = blockIdx.x;
    if (b < NTOK) {
        __shared__ float wmax[4];
        const int row = b;
        const int tid = threadIdx.x;
        const float* p = x + (size_t)row * D_MODEL + tid * 16;
        float4v v0 = *(const float4v*)(p);
        float4v v1 = *(const float4v*)(p + 4);
        float4v v2 = *(const float4v*)(p + 8);
        float4v v3 = *(const float4v*)(p + 12);
        float m = 0.f;
#pragma unroll
        for (int e = 0; e < 4; ++e)
            m = fmaxf(m, fmaxf(fmaxf(fabsf(v0[e]), fabsf(v1[e])),
                               fmaxf(fabsf(v2[e]), fabsf(v3[e]))));
#pragma unroll
        for (int off = 1; off < 64; off <<= 1)
            m = fmaxf(m, __shfl_xor(m, off));
        if ((tid & 63) == 0) wmax[tid >> 6] = m;
        __syncthreads();
        m = fmaxf(fmaxf(wmax[0], wmax[1]), fmaxf(wmax[2], wmax[3]));
        if (tid == 0) xsc[row] = m * (1.0f / 127.0f);
        const float inv = (m > 0.f) ? (127.0f / m) : 0.f;
        i32x4 o;
        float4v vs[4] = {v0, v1, v2, v3};
#pragma unroll
        for (int j = 0; j < 4; ++j) {
            u32 w = 0;
#pragma unroll
            for (int e = 0; e < 4; ++e) {
                int q = (int)rintf(vs[j][e] * inv);
                q = q > 127 ? 127 : (q < -127 ? -127 : q);
                w |= (u32)(q & 255) << (8 * e);
            }
            o[j] = (int)w;
        }
        *(i32x4*)(xq + (size_t)row * D_MODEL + tid * 16) = o;
        return;
    }
    // ---- weight conversion blocks ----
    const int cb = b - NTOK;
    const int* w; s8* o; int bb;
    if (cb < wgrid) { w = gw; o = wg8; bb = cb; }
    else            { w = uw; o = wu8; bb = cb - wgrid; }
    int i = (bb * 256 + threadIdx.x) * 8;
    int4v a = *(const int4v*)(w + i);
    int4v c = *(const int4v*)(w + i + 4);
    u32 w0 = 0, w1 = 0;
#pragma unroll
    for (int e = 0; e < 4; ++e) {
        w0 |= (u32)(a[e] & 255) << (8 * e);
        w1 |= (u32)(c[e] & 255) << (8 * e);
    }
    *(u32x2*)(o + i) = (u32x2){w0, w1};
}

// =====================================================================
// FUSED gate+up GEMM, INT8 (R16-proven) + TAIL BLOCKS converting dw
// int32 -> bf16 in spare HBM BW (R17-proven). GEMM: 256 tokens x 128
// f-cols, BK=64, mfma_i32_16x16x64_i8, 64 KiB LDS dbuf, 2-phase
// schedule, vmcnt(3) gate, conflict-free swizzle (granule p of row R
// holds p^((R>>1)&3); stage inverse (lane&3)^((lane>>3)&3)).
// Epilogue: h = bf16( silu(acc_g*xsc[row]*gs) * acc_u*xsc[row]*us ).
// =====================================================================

#define BAR   __builtin_amdgcn_s_barrier()
#define PRIO1 __builtin_amdgcn_s_setprio(1)
#define PRIO0 __builtin_amdgcn_s_setprio(0)
#define VMC(N)  asm volatile("s_waitcnt vmcnt(" #N ")" ::: "memory")

#define RD_A8(AA, BUF, MH) {                                                  \
  _Pragma("unroll") for (int mm = 0; mm < 4; ++mm)                            \
    AA[mm] = *(const i32x4*)&lds8[(BUF)*32768 + (MH)*8192 + mm*1024 + adA]; }

#define RD_B8(BB, BUF) {                                                      \
  _Pragma("unroll") for (int nn = 0; nn < 4; ++nn)                            \
    BB[nn] = *(const i32x4*)&lds8[(BUF)*32768 + 16384 + (nn>>1)*8192 +        \
                                  (nn&1)*1024 + adB]; }

#define MFMA_I8(MH, AA, BB)                                                   \
  _Pragma("unroll") for (int mm = 0; mm < 4; ++mm)                            \
  _Pragma("unroll") for (int nn = 0; nn < 4; ++nn)                            \
    acc[(MH)*4+mm][nn] = __builtin_amdgcn_mfma_i32_16x16x64_i8(               \
        AA[mm], BB[nn], acc[(MH)*4+mm][nn], 0, 0, 0);

#define STAGE_AH(BUF, MH, K0) {                                               \
  gload16(xq + (size_t)(bm*256 + (MH)*128 + wave*16 + (lane>>2))*K + (K0) + asw, \
          &lds8[(BUF)*32768 + (MH)*8192 + wave*1024 + lane*16]); }

#define STAGE_B2(BUF, K0) {                                                   \
  gload16(b0base + (size_t)(wave*16 + (lane>>2))*K + (K0) + asw,              \
          &lds8[(BUF)*32768 + 16384 + wave*1024 + lane*16]);                  \
  gload16(b1base + (size_t)(wave*16 + (lane>>2))*K + (K0) + asw,              \
          &lds8[(BUF)*32768 + 24576 + wave*1024 + lane*16]); }

#define TILE_I8(CUR, NXT, T) {                                                \
  RD_A8(a0, CUR, 0); RD_B8(bb, CUR);                                          \
  if ((T)+1 < nt) STAGE_AH(NXT, 1, ((T)+1) << 6);                             \
  BAR; PRIO1; MFMA_I8(0, a0, bb); PRIO0; BAR;                                 \
  RD_A8(a1, CUR, 1);                                                          \
  if ((T)+2 < nt) { STAGE_AH(CUR, 0, ((T)+2) << 6);                           \
                    STAGE_B2(CUR, ((T)+2) << 6); }                            \
  BAR; PRIO1; MFMA_I8(1, a1, bb); PRIO0;                                      \
  if ((T)+2 < nt) { VMC(3); } else { VMC(0); }                                \
  BAR; }

__global__ __launch_bounds__(512, 2) void k_fusedgu_i8(
    const s8* __restrict__ xq,
    const s8* __restrict__ wg8, const s8* __restrict__ wu8,
    const float* __restrict__ gs, const float* __restrict__ us,
    const float* __restrict__ xsc,
    u16* __restrict__ hb, int K, int NBN, int ldc,
    const int* __restrict__ dw, u16* __restrict__ wbD, int nwgemm)
{
    __shared__ __align__(16) char lds8[65536];   // 64 KiB

    // ---- tail blocks: dw int32 -> bf16 (grid-stride, race-free) ----
    if ((int)blockIdx.x >= nwgemm) {
        const long long tidg = (long long)(blockIdx.x - nwgemm) * 512 + threadIdx.x;
        const long long stride = (long long)CVT_BLOCKS * 512 * 8;
        const long long n = (long long)D_FF * D_MODEL;
        for (long long i = tidg * 8; i < n; i += stride) {
            int4v a = *(const int4v*)(dw + i);
            int4v b = *(const int4v*)(dw + i + 4);
            ushort8 o;
            o[0] = bf16_from_int(a[0]); o[1] = bf16_from_int(a[1]);
            o[2] = bf16_from_int(a[2]); o[3] = bf16_from_int(a[3]);
            o[4] = bf16_from_int(b[0]); o[5] = bf16_from_int(b[1]);
            o[6] = bf16_from_int(b[2]); o[7] = bf16_from_int(b[3]);
            *(ushort8*)(wbD + i) = o;
        }
        return;
    }

    const int tid  = threadIdx.x;
    const int lane = tid & 63;
    const int wave = tid >> 6;          // 0..7
    const int wm   = wave >> 2;         // 0..1
    const int wn   = wave & 3;          // 0..3

    // XCD-aware bijective swizzle; bm slow, bn fast
    const int nwg  = 16 * NBN;
    const int orig = blockIdx.x;
    const int qq   = nwg >> 3, rr = nwg & 7;
    const int xcd  = orig & 7;
    const int swz  = (xcd < rr ? xcd*(qq+1) : rr*(qq+1) + (xcd-rr)*qq) + (orig >> 3);
    const int bm   = swz / NBN;
    const int bn   = swz % NBN;

    // fragment-read constants (bytes) — conflict-free swizzle
    const int r    = lane & 15;
    const int sQ   = lane >> 4;                        // k-granule 0..3
    const int qsw  = (sQ ^ ((r >> 1) & 3)) * 16;       // swizzled granule
    const int adA  = (wm*64 + r) * 64 + qsw;
    const int adB  = (wn*32 + r) * 64 + qsw;

    // stage source swizzle (inverse involution)
    const int asw  = ((lane & 3) ^ ((lane >> 3) & 3)) * 16;

    const s8* b0base = wg8 + (size_t)(bn*128) * K;
    const s8* b1base = wu8 + (size_t)(bn*128) * K;

    i32x4 acc[8][4];
#pragma unroll
    for (int m = 0; m < 8; ++m)
#pragma unroll
        for (int n = 0; n < 4; ++n) acc[m][n] = (i32x4){0, 0, 0, 0};

    const int nt = K >> 6;              // 64 for K=4096 (even)

    // prologue: tile0 fully [4 gloads], tile1 {Ah0, B} [3]
    STAGE_AH(0, 0, 0); STAGE_AH(0, 1, 0); STAGE_B2(0, 0);
    STAGE_AH(1, 0, 64); STAGE_B2(1, 64);
    VMC(3);
    BAR;

    i32x4 a0[4], a1[4], bb[4];
    for (int t = 0; t < nt; t += 2) {
        TILE_I8(0, 1, t);
        TILE_I8(1, 0, t + 1);
    }

    // epilogue: n=0,1 -> gate; n=2,3 -> up (same f-cols)
    const int f0 = bn*128 + wn*32 + r;
    const float gsc0 = gs[f0],      usc0 = us[f0];
    const float gsc1 = gs[f0 + 16], usc1 = us[f0 + 16];
#pragma unroll
    for (int m = 0; m < 8; ++m) {
        const int row = bm*256 + (m>>2)*128 + wm*64 + (m&3)*16 + sQ*4;
#pragma unroll
        for (int q = 0; q < 4; ++q) {
            const float xs = xsc[row + q];
            const float g0 = (float)acc[m][0][q] * xs * gsc0;
            const float u0 = (float)acc[m][2][q] * xs * usc0;
            const float g1 = (float)acc[m][1][q] * xs * gsc1;
            const float u1 = (float)acc[m][3][q] * xs * usc1;
            const float h0 = (g0 / (1.0f + __expf(-g0))) * u0;
            const float h1 = (g1 / (1.0f + __expf(-g1))) * u1;
            hb[(size_t)(row + q) * ldc + f0]      = bf16_rn(h0);
            hb[(size_t)(row + q) * ldc + f0 + 16] = bf16_rn(h1);
        }
    }
}

// =====================================================================
// DOWN GEMM (bf16) — exact R12 structure (proven): 256x256, 2-phase,
// vmcnt(6), XOR-granule swizzle, gload_lds staging, setprio.
// out[m,d] = (h . dw^T)[m,d] * ds[d]   (fp32 out)
// =====================================================================

#define READA(AA, BUF, MH) {                                                  \
  _Pragma("unroll") for (int mm = 0; mm < 4; ++mm) {                          \
    AA[mm][0] = *(const bf16x8*)&lds[(BUF)*32768 + (MH)*8192 + mm*1024 + aoffE + g0E]; \
    AA[mm][1] = *(const bf16x8*)&lds[(BUF)*32768 + (MH)*8192 + mm*1024 + aoffE + g1E]; } }

#define READB(BB, BUF, NH) {                                                  \
  _Pragma("unroll") for (int nn = 0; nn < 2; ++nn) {                          \
    BB[nn][0] = *(const bf16x8*)&lds[(BUF)*32768 + 16384 + (NH)*8192 + nn*1024 + boffE + g0E]; \
    BB[nn][1] = *(const bf16x8*)&lds[(BUF)*32768 + 16384 + (NH)*8192 + nn*1024 + boffE + g1E]; } }

#define MFMA16(MH, NH, AA, BB)                                                \
  _Pragma("unroll") for (int mm = 0; mm < 4; ++mm)                            \
  _Pragma("unroll") for (int nn = 0; nn < 2; ++nn)                            \
  _Pragma("unroll") for (int kk = 0; kk < 2; ++kk)                            \
    acc[(MH)*4+mm][(NH)*2+nn] = __builtin_amdgcn_mfma_f32_16x16x32_bf16(      \
        AA[mm][kk], BB[nn][kk], acc[(MH)*4+mm][(NH)*2+nn], 0, 0, 0);

#define REGA(BUF, H) ((BUF)*32768 + (H)*8192)
#define REGB(BUF, H) ((BUF)*32768 + 16384 + (H)*8192)

#define STAGE_A(BUF, MH, K0) {                                                \
  const u16* _s = A + a_sbase + (size_t)(MH)*128*K + (K0);                    \
  gload16(_s,                &lds[REGA(BUF, MH) + wave*512]);                 \
  gload16(_s + (size_t)64*K, &lds[REGA(BUF, MH) + (8+wave)*512]); }

#define STAGE_B(BUF, NH, K0) {                                                \
  const u16* _s = ((NH) ? b1base : b0base) + (K0);                            \
  gload16(_s,                &lds[REGB(BUF, NH) + wave*512]);                 \
  gload16(_s + (size_t)64*K, &lds[REGB(BUF, NH) + (8+wave)*512]); }

#define TILE2(CUR, NXT, T) {                                                  \
  READA(a0, CUR, 0); READB(b0, CUR, 0); READB(b1, CUR, 1);                    \
  if ((T)+1 < nt) STAGE_A(NXT, 1, ((T)+1) << 6);                              \
  BAR; PRIO1;                                                                 \
  MFMA16(0, 0, a0, b0); MFMA16(0, 1, a0, b1);                                 \
  PRIO0; BAR;                                                                 \
  READA(a1, CUR, 1);                                                          \
  if ((T)+2 < nt) { STAGE_A(CUR, 0, ((T)+2) << 6);                            \
                    STAGE_B(CUR, 0, ((T)+2) << 6);                            \
                    STAGE_B(CUR, 1, ((T)+2) << 6); }                          \
  BAR; PRIO1;                                                                 \
  MFMA16(1, 1, a1, b1); MFMA16(1, 0, a1, b0);                                 \
  PRIO0;                                                                      \
  if ((T)+2 < nt) { VMC(6); } else { VMC(0); }                                \
  BAR; }

__global__ __launch_bounds__(512, 2) void k_down256(
    const u16* __restrict__ A, const u16* __restrict__ B0,
    const float* __restrict__ sc0, float* __restrict__ of32,
    int K, int NBN, int ldc)
{
    __shared__ __align__(16) u16 lds[65536];   // 128 KiB

    const int tid  = threadIdx.x;
    const int lane = tid & 63;
    const int wave = tid >> 6;
    const int wm   = wave >> 2;
    const int wn   = wave & 3;

    const int nwg  = 16 * NBN;
    const int orig = blockIdx.x;
    const int qq   = nwg >> 3, rr = nwg & 7;
    const int xcd  = orig & 7;
    const int swz  = (xcd < rr ? xcd*(qq+1) : rr*(qq+1) + (xcd-rr)*qq) + (orig >> 3);
    const int bm   = swz / NBN;
    const int bn   = swz % NBN;

    const int r    = lane & 15;
    const int sQ   = lane >> 4;
    const int x7   = r & 7;
    const int g0E  = (sQ ^ x7) * 8;
    const int g1E  = ((4 | sQ) ^ x7) * 8;
    const int aoffE = (wm*64 + r) * 64;
    const int boffE = (wn*32 + r) * 64;

    const int lrow = lane >> 3;
    const int goff = ((lane & 7) ^ lrow) * 8;
    const size_t a_sbase = (size_t)(bm*256 + wave*8 + lrow) * K + goff;
    const u16* b0base = B0 + (size_t)(bn*256 +       wave*8 + lrow) * K + goff;
    const u16* b1base = B0 + (size_t)(bn*256 + 128 + wave*8 + lrow) * K + goff;

    f32x4 acc[8][4];
#pragma unroll
    for (int m = 0; m < 8; ++m)
#pragma unroll
        for (int n = 0; n < 4; ++n) acc[m][n] = (f32x4){0.f, 0.f, 0.f, 0.f};

    const int nt = K >> 6;              // 172 for K=11008 (even)

    STAGE_A(0, 0, 0); STAGE_A(0, 1, 0); STAGE_B(0, 0, 0); STAGE_B(0, 1, 0);
    STAGE_A(1, 0, 64); STAGE_B(1, 0, 64); STAGE_B(1, 1, 64);
    VMC(6);
    BAR;

    bf16x8 a0[4][2], a1[4][2], b0[2][2], b1[2][2];
    for (int t = 0; t < nt; t += 2) {
        TILE2(0, 1, t);
        TILE2(1, 0, t + 1);
    }

#pragma unroll
    for (int n = 0; n < 4; ++n) {
        const int col = bn*256 + (n>>1)*128 + wn*32 + (n&1)*16 + r;
        const float sc = sc0[col];
#pragma unroll
        for (int m = 0; m < 8; ++m) {
            const int row = bm*256 + (m>>2)*128 + wm*64 + (m&3)*16 + sQ*4;
#pragma unroll
            for (int q = 0; q < 4; ++q)
                of32[(size_t)(row + q) * ldc + col] = acc[m][n][q] * sc;
        }
    }
}

extern "C" void kernel_launch(void* const* d_in, const int* in_sizes, int n_in,
                              void* d_out, int out_size, void* d_ws, size_t ws_size,
                              hipStream_t stream) {
    const float* x  = (const float*)d_in[0];
    const int*   gw = (const int*)d_in[1];
    const float* gs = (const float*)d_in[2];
    const int*   uw = (const int*)d_in[3];
    const float* us = (const float*)d_in[4];
    const int*   dw = (const int*)d_in[5];
    const float* ds = (const float*)d_in[6];
    float* out = (float*)d_out;

    const size_t XQ = (size_t)NTOK * D_MODEL;       // 16.8 MB  x s8
    const size_t W8 = (size_t)D_FF * D_MODEL;       // 45.1 MB  weight s8
    const size_t WD = (size_t)D_FF * D_MODEL * 2;   // 90.2 MB  down weight bf16
    const size_t HB = (size_t)NTOK * D_FF * 2;      // 90.2 MB  h bf16
    const size_t SC = (size_t)NTOK * 4;             // 16 KB    per-token x scale
    if (ws_size < XQ + 2 * W8 + WD + HB + SC) return;  // loud failure

    char* ws = (char*)d_ws;
    s8*  xq   = (s8*)ws;
    s8*  wg8  = (s8*)(ws + XQ);
    s8*  wu8  = (s8*)(ws + XQ + W8);
    u16* wbD  = (u16*)(ws + XQ + 2 * W8);
    u16* hb   = (u16*)(ws + XQ + 2 * W8 + WD);
    float* xsc = (float*)(ws + XQ + 2 * W8 + WD + HB);

    const int wn_elems = D_FF * D_MODEL;            // 45,088,768
    const int wgrid = wn_elems / (8 * 256);
    const int nwgemm = 16 * (D_FF / 128);           // 1376

    // merged prep: x per-token quantize + gate/up weight conversion
    k_prep<<<NTOK + 2 * wgrid, 256, 0, stream>>>(
        x, xq, xsc, gw, uw, wg8, wu8, wgrid);

    // fused i8 GEMM + tail blocks converting dw -> bf16 in spare HBM BW
    k_fusedgu_i8<<<nwgemm + CVT_BLOCKS, 512, 0, stream>>>(
        xq, wg8, wu8, gs, us, xsc, hb, D_MODEL, D_FF / 128, D_FF,
        dw, wbD, nwgemm);

    // down (bf16): out = (h . dw^T) * ds
    k_down256<<<16 * (D_MODEL / 256), 512, 0, stream>>>(
        hb, wbD, ds, out, D_FF, D_MODEL / 256, D_MODEL);
}